// Round 1
// 555.325 us; speedup vs baseline: 1.0500x; 1.0500x over previous
//
#include <hip/hip_runtime.h>
#include <math.h>

// Problem constants
#define BB   16
#define CIN  64
#define HH   256
#define WW   256
#define MMOD 16   // modes per dim kept

// d_ws layout (floats):
//   TW2 : [256 w][16 q][2]             = 8192 floats (32 KB)
//   Xg  : [512 mode][64 c][16 b][2]    = 1,048,576 floats (4 MB)
//   Yg  : [16 b][64 d][512 mode][2]    = 1,048,576 floats (4 MB)
//   Wt  : [512 mode][64 d][64 c][2]    = 4,194,304 floats (16 MB)

// ---------------------------------------------------------------- twiddles
__global__ __launch_bounds__(256) void k_twiddle(float* __restrict__ TW2) {
    int idx = blockIdx.x * 256 + threadIdx.x;   // 4096 entries
    int w = idx >> 4, q = idx & 15;
    int k = (q * w) & 255;
    float s, c;
    sincospif((float)k * (1.0f / 128.0f), &s, &c);  // sin/cos(2*pi*k/256)
    TW2[2 * idx]     = c;
    TW2[2 * idx + 1] = s;
}

// ------------------------------------------------- weight transpose: w -> Wt
// input  w1/w2: [(d*64+c)][t*16+q] complex (row stride 256 complex)
// output Wt   : [mode=t*16+q (w1: 0..255, w2: 256..511)][d*64+c] complex
// 32x32 complex tiles through LDS; both global sides fully coalesced.
__global__ __launch_bounds__(256) void k_wt(const float* __restrict__ w1,
                                            const float* __restrict__ w2,
                                            float* __restrict__ Wt) {
    __shared__ float2 tile[32][33];
    const int tid = threadIdx.x;
    const int bt = blockIdx.x & 15;      // B tile: (t,q) in [0,512)
    const int at = blockIdx.x >> 4;      // A tile: (d,c) in [0,4096)
    const int b0 = bt * 32, a0 = at * 32;
    const float2* __restrict__ src = (const float2*)((b0 < 256) ? w1 : w2);
    const int bbase = b0 & 255;          // local row inside selected weight
#pragma unroll
    for (int k = 0; k < 4; k++) {
        int idx = k * 256 + tid;
        int r = idx >> 5, cl = idx & 31;            // r: A offset, cl: B offset
        tile[r][cl] = src[(size_t)(a0 + r) * 256 + bbase + cl];
    }
    __syncthreads();
    float2* __restrict__ dst = (float2*)Wt;
#pragma unroll
    for (int k = 0; k < 4; k++) {
        int idx = k * 256 + tid;
        int r = idx >> 5, cl = idx & 31;            // r: B offset, cl: A offset
        dst[(size_t)(b0 + r) * 4096 + a0 + cl] = tile[cl][r];
    }
}

// ------------------------------------------------- forward partial DFT: x -> X
// one block per (b,c) image
__global__ __launch_bounds__(256) void k_fwd(const float* __restrict__ x,
                                             const float* __restrict__ TW2,
                                             float* __restrict__ Xg) {
    __shared__ float  smem[256 * 34];   // x-slab [256][33] then P [256][34]
    __shared__ float2 Ecs[256];         // e^{2*pi*i*k/256}

    const int tid = threadIdx.x;
    const int img = blockIdx.x;         // b*64 + c
    const float* __restrict__ xi = x + (size_t)img * (HH * WW);

    {   // build unit-root table (used in Phase B)
        float s, c;
        sincospif((float)tid * (1.0f / 128.0f), &s, &c);
        Ecs[tid] = make_float2(c, s);
    }

    // ---- Phase A (radix-2 over w): fold w <-> w+128, sign (-1)^q.
    // P[h,q] = sum_{w<128} tw(q,w) * (x[h,w] + (-1)^q x[h,w+128])
    float pr[16], pi[16];
#pragma unroll
    for (int q = 0; q < 16; q++) { pr[q] = 0.f; pi[q] = 0.f; }

    for (int s = 0; s < 8; s++) {        // slab: base cols [16s,16s+16) + mirrors
        __syncthreads();                 // previous slab fully consumed
        // stage 256 rows x 32 cols (16 base + 16 mirror), 64B segments
#pragma unroll
        for (int j = 0; j < 8; j++) {
            int flat = j * 256 + tid;    // 2048 float4s
            int h = flat >> 3, f4 = flat & 7;
            int col = 16 * s + ((f4 & 4) << 5) + (f4 & 3) * 4;  // +128 for f4>=4
            float4 v = *(const float4*)(xi + (size_t)h * WW + col);
            float* p = &smem[h * 33 + f4 * 4];
            p[0] = v.x; p[1] = v.y; p[2] = v.z; p[3] = v.w;
        }
        __syncthreads();
        const float* __restrict__ twp = TW2 + s * 512;   // uniform -> s_load
#pragma unroll 2
        for (int wl = 0; wl < 16; wl++) {
            float y0 = smem[tid * 33 + wl];        // x[h, 16s+wl]
            float y1 = smem[tid * 33 + 16 + wl];   // x[h, 16s+wl+128]
            float sp = y0 + y1, sm = y0 - y1;
#pragma unroll
            for (int q = 0; q < 16; q++) {
                float sel = (q & 1) ? sm : sp;     // compile-time select
                float cc = twp[wl * 32 + 2 * q];
                float ss = twp[wl * 32 + 2 * q + 1];
                pr[q] = fmaf(sel,  cc, pr[q]);
                pi[q] = fmaf(sel, -ss, pi[q]);
            }
        }
    }

    // ---- dump P to LDS (padded: row stride 34 floats = 17 complex)
    __syncthreads();
#pragma unroll
    for (int q = 0; q < 16; q++) {
        smem[tid * 34 + 2 * q]     = pr[q];
        smem[tid * 34 + 2 * q + 1] = pi[q];
    }
    __syncthreads();

    // ---- Phase B (radix-2 over h): both t of this thread share parity(tp),
    // so only one of (P[h] +/- P[h+128]) is needed.
    {
        const int q  = tid & 15;
        const int tp = tid >> 4;
        const int t0 = tp;
        const int t1 = 240 + tp;
        const float sg = (tp & 1) ? -1.f : 1.f;
        float x0r = 0.f, x0i = 0.f, x1r = 0.f, x1i = 0.f;
        for (int h = 0; h < 128; h++) {
            float pra = smem[h * 34 + 2 * q];
            float pia = smem[h * 34 + 2 * q + 1];
            float prb = smem[(h + 128) * 34 + 2 * q];
            float pib = smem[(h + 128) * 34 + 2 * q + 1];
            float u = fmaf(sg, prb, pra);
            float v = fmaf(sg, pib, pia);
            float2 e0 = Ecs[(t0 * h) & 255];
            float2 e1 = Ecs[(t1 * h) & 255];
            x0r = fmaf(u, e0.x, fmaf(v,  e0.y, x0r));
            x0i = fmaf(v, e0.x, fmaf(u, -e0.y, x0i));
            x1r = fmaf(u, e1.x, fmaf(v,  e1.y, x1r));
            x1i = fmaf(v, e1.x, fmaf(u, -e1.y, x1i));
        }
        const float sc = 1.0f / 256.0f;
        const int b = img >> 6, c = img & 63;
        size_t o0 = ((size_t)(tp * 16 + q) * 64 + c) * 16 + b;         // mode tp
        size_t o1 = ((size_t)((16 + tp) * 16 + q) * 64 + c) * 16 + b;  // mode 16+tp
        Xg[2 * o0]     = x0r * sc;
        Xg[2 * o0 + 1] = x0i * sc;
        Xg[2 * o1]     = x1r * sc;
        Xg[2 * o1 + 1] = x1i * sc;
    }
}

// ------------------------------------------------- per-mode channel mix: X -> Y
// one block per mode (tIdx*16+q), Y[b,d] = sum_c X[c,b] * W[d,c]
__global__ __launch_bounds__(256) void k_mix(const float* __restrict__ Xg,
                                             const float* __restrict__ Wt,
                                             float* __restrict__ Yg) {
    __shared__ float Xs[64 * 34];    // [c][b] padded (17 complex stride)
    __shared__ float Ws[64 * 130];   // [d][c] padded (65 complex stride)

    const int tid  = threadIdx.x;
    const int mode = blockIdx.x;

#pragma unroll
    for (int j = 0; j < 4; j++) {    // X: 1024 complex contiguous
        int i = j * 256 + tid;       // c*16+b
        float2 v = ((const float2*)Xg)[(size_t)mode * 1024 + i];
        int c = i >> 4, b = i & 15;
        Xs[c * 34 + 2 * b] = v.x; Xs[c * 34 + 2 * b + 1] = v.y;
    }
#pragma unroll
    for (int j = 0; j < 16; j++) {   // W: 4096 complex contiguous (transposed)
        int i = j * 256 + tid;       // d*64+c
        float2 v = ((const float2*)Wt)[(size_t)mode * 4096 + i];
        int d = i >> 6, c = i & 63;
        Ws[d * 130 + 2 * c] = v.x; Ws[d * 130 + 2 * c + 1] = v.y;
    }
    __syncthreads();

    const int b = tid & 15, dg = tid >> 4;
    float yr[4] = {0, 0, 0, 0}, yi[4] = {0, 0, 0, 0};
    for (int c = 0; c < 64; c++) {
        float xr = Xs[c * 34 + 2 * b];
        float xi = Xs[c * 34 + 2 * b + 1];
#pragma unroll
        for (int j = 0; j < 4; j++) {
            int d = dg + 16 * j;
            float wr = Ws[d * 130 + 2 * c];
            float wi = Ws[d * 130 + 2 * c + 1];
            yr[j] = fmaf(xr, wr, fmaf(xi, -wi, yr[j]));
            yi[j] = fmaf(xr, wi, fmaf(xi,  wr, yi[j]));
        }
    }
#pragma unroll
    for (int j = 0; j < 4; j++) {
        int d = dg + 16 * j;
        size_t o = ((size_t)(b * 64 + d) * 512 + mode);
        Yg[2 * o] = yr[j]; Yg[2 * o + 1] = yi[j];
    }
}

// ------------------------------------------------- inverse: Y -> out
// one block per (b,d) image
__global__ __launch_bounds__(256) void k_inv(const float* __restrict__ Yg,
                                             const float* __restrict__ TW2,
                                             float* __restrict__ out) {
    __shared__ float2 Ecs[256];
    __shared__ float  stage[256 * 33];

    const int tid = threadIdx.x;
    const int img = blockIdx.x;      // b*64 + d
    {
        float s, c;
        sincospif((float)tid * (1.0f / 128.0f), &s, &c);
        Ecs[tid] = make_float2(c, s);
    }
    const float* __restrict__ Y = Yg + (size_t)img * 1024;  // 512 complex

    // ---- Phase D: g[h,q] = sum_{t in S} Y[t,q] e^{+2pi i t h/256}, thread h=tid
    float gr[16], gi[16];
#pragma unroll
    for (int q = 0; q < 16; q++) { gr[q] = 0.f; gi[q] = 0.f; }
    __syncthreads();   // Ecs ready
    const int h = tid;
    for (int j = 0; j < 32; j++) {
        int t = (j < 16) ? j : (224 + j);      // 240..255 for bottom block
        float2 e = Ecs[(t * h) & 255];
#pragma unroll
        for (int q = 0; q < 16; q++) {
            float yr = Y[j * 32 + 2 * q];      // uniform -> s_load
            float yv = Y[j * 32 + 2 * q + 1];
            gr[q] = fmaf(yr, e.x, fmaf(yv, -e.y, gr[q]));
            gi[q] = fmaf(yv, e.x, fmaf(yr,  e.y, gi[q]));
        }
    }

    // ---- Phase E (radix-2 over w): out[w]=ae+ao, out[w+128]=ae-ao
    const size_t obase = (size_t)img * (HH * WW);
    const float k2 = 2.0f / 256.0f;
    for (int s = 0; s < 8; s++) {
        const float* __restrict__ twp = TW2 + s * 512;   // uniform -> s_load
#pragma unroll 2
        for (int wl = 0; wl < 16; wl++) {
            float ae = 0.5f * gr[0];
            float ao = 0.f;
#pragma unroll
            for (int q = 1; q < 16; q++) {
                float cc = twp[wl * 32 + 2 * q];
                float ss = twp[wl * 32 + 2 * q + 1];
                if (q & 1) ao = fmaf(gr[q], cc, fmaf(gi[q], -ss, ao));
                else       ae = fmaf(gr[q], cc, fmaf(gi[q], -ss, ae));
            }
            stage[h * 33 + wl]      = (ae + ao) * k2;
            stage[h * 33 + 16 + wl] = (ae - ao) * k2;
        }
        __syncthreads();
#pragma unroll
        for (int j = 0; j < 8; j++) {
            int flat = j * 256 + tid;    // 2048 float4s
            int hh = flat >> 3, f4 = flat & 7;
            int col = 16 * s + ((f4 & 4) << 5) + (f4 & 3) * 4;  // +128 for f4>=4
            const float* p = &stage[hh * 33 + f4 * 4];
            float4 v; v.x = p[0]; v.y = p[1]; v.z = p[2]; v.w = p[3];
            *(float4*)(out + obase + (size_t)hh * WW + col) = v;
        }
        __syncthreads();
    }
}

extern "C" void kernel_launch(void* const* d_in, const int* in_sizes, int n_in,
                              void* d_out, int out_size, void* d_ws, size_t ws_size,
                              hipStream_t stream) {
    const float* x  = (const float*)d_in[0];
    const float* w1 = (const float*)d_in[1];
    const float* w2 = (const float*)d_in[2];
    float* outp = (float*)d_out;

    float* TW2 = (float*)d_ws;           // 8192 floats
    float* Xg  = TW2 + 8192;             // 1,048,576 floats
    float* Yg  = Xg + 1048576;           // 1,048,576 floats
    float* Wt  = Yg + 1048576;           // 4,194,304 floats

    k_twiddle<<<16,   256, 0, stream>>>(TW2);
    k_wt     <<<2048, 256, 0, stream>>>(w1, w2, Wt);
    k_fwd    <<<BB * CIN, 256, 0, stream>>>(x, TW2, Xg);
    k_mix    <<<512,  256, 0, stream>>>(Xg, Wt, Yg);
    k_inv    <<<BB * CIN, 256, 0, stream>>>(Yg, TW2, outp);
}

// Round 2
// 550.228 us; speedup vs baseline: 1.0598x; 1.0093x over previous
//
#include <hip/hip_runtime.h>
#include <math.h>

// Problem constants
#define BB   16
#define CIN  64
#define HH   256
#define WW   256
#define MMOD 16   // modes per dim kept

// d_ws layout (floats):
//   TW2 : [256 w][16 q][2]             = 8192 floats (32 KB)
//   Xg  : [512 mode][64 c][16 b][2]    = 1,048,576 floats (4 MB)
//   Yg  : [16 b][64 d][512 mode][2]    = 1,048,576 floats (4 MB)
//   Wt  : [512 mode][64 d][64 c][2]    = 4,194,304 floats (16 MB)

// ---------------------------------------------------------------- twiddles
__global__ __launch_bounds__(256) void k_twiddle(float* __restrict__ TW2) {
    int idx = blockIdx.x * 256 + threadIdx.x;   // 4096 entries
    int w = idx >> 4, q = idx & 15;
    int k = (q * w) & 255;
    float s, c;
    sincospif((float)k * (1.0f / 128.0f), &s, &c);  // sin/cos(2*pi*k/256)
    TW2[2 * idx]     = c;
    TW2[2 * idx + 1] = s;
}

// ------------------------------------------------- weight transpose: w -> Wt
// input  w1/w2: [(d*64+c)][t*16+q] complex (row stride 256 complex)
// output Wt   : [mode=t*16+q (w1: 0..255, w2: 256..511)][d*64+c] complex
__global__ __launch_bounds__(256) void k_wt(const float* __restrict__ w1,
                                            const float* __restrict__ w2,
                                            float* __restrict__ Wt) {
    __shared__ float2 tile[32][33];
    const int tid = threadIdx.x;
    const int bt = blockIdx.x & 15;      // B tile: (t,q) in [0,512)
    const int at = blockIdx.x >> 4;      // A tile: (d,c) in [0,4096)
    const int b0 = bt * 32, a0 = at * 32;
    const float2* __restrict__ src = (const float2*)((b0 < 256) ? w1 : w2);
    const int bbase = b0 & 255;          // local row inside selected weight
#pragma unroll
    for (int k = 0; k < 4; k++) {
        int idx = k * 256 + tid;
        int r = idx >> 5, cl = idx & 31;            // r: A offset, cl: B offset
        tile[r][cl] = src[(size_t)(a0 + r) * 256 + bbase + cl];
    }
    __syncthreads();
    float2* __restrict__ dst = (float2*)Wt;
#pragma unroll
    for (int k = 0; k < 4; k++) {
        int idx = k * 256 + tid;
        int r = idx >> 5, cl = idx & 31;            // r: B offset, cl: A offset
        dst[(size_t)(b0 + r) * 4096 + a0 + cl] = tile[cl][r];
    }
}

// ------------------------------------------------- forward partial DFT: x -> X
// one block per (b,c) image.
// Async-staged Phase A: prefetch slab s+1 into registers while computing slab s;
// raw barriers (lgkm-only waits) keep global loads in flight across barriers.
__global__ __launch_bounds__(256) void k_fwd(const float* __restrict__ x,
                                             const float* __restrict__ TW2,
                                             float* __restrict__ Xg) {
    __shared__ float  smem[256 * 34];   // x-slab [256][33] then P/UV [256][34]
    __shared__ float2 Ecs[256];         // e^{2*pi*i*k/256}

    const int tid = threadIdx.x;
    const int img = blockIdx.x;         // b*64 + c
    const float* __restrict__ xi = x + (size_t)img * (HH * WW);

    {   // build unit-root table (used in Phase B)
        float s, c;
        sincospif((float)tid * (1.0f / 128.0f), &s, &c);
        Ecs[tid] = make_float2(c, s);
    }

    float pr[16], pi[16];
#pragma unroll
    for (int q = 0; q < 16; q++) { pr[q] = 0.f; pi[q] = 0.f; }

    // staging geometry: thread loads float4 at (row j*32+hb, col 16s + colb)
    const int f4   = tid & 7;
    const int hb   = tid >> 3;                           // 0..31
    const int colb = ((f4 & 4) << 5) + (f4 & 3) * 4;     // 0..12 or 128..140

    float4 r[8];
#pragma unroll
    for (int j = 0; j < 8; j++)       // prefetch slab 0
        r[j] = *(const float4*)(xi + (size_t)(j * 32 + hb) * WW + colb);

    for (int s = 0; s < 8; s++) {
        // previous slab fully consumed (this wave's LDS reads retired) + barrier
        asm volatile("s_waitcnt lgkmcnt(0)" ::: "memory");
        __builtin_amdgcn_s_barrier();
        // stage slab s from regs (compiler inserts vmcnt waits for r[] deps)
#pragma unroll
        for (int j = 0; j < 8; j++) {
            float* p = &smem[(j * 32 + hb) * 33 + f4 * 4];
            p[0] = r[j].x; p[1] = r[j].y; p[2] = r[j].z; p[3] = r[j].w;
        }
        // issue prefetch of slab s+1 (stays in flight through the compute below)
        if (s < 7) {
            const float* __restrict__ xs = xi + 16 * (s + 1) + colb;
#pragma unroll
            for (int j = 0; j < 8; j++)
                r[j] = *(const float4*)(xs + (size_t)(j * 32 + hb) * WW);
        }
        asm volatile("s_waitcnt lgkmcnt(0)" ::: "memory");
        __builtin_amdgcn_s_barrier();
        // ---- Phase A (radix-2 over w): P[h,q] += tw(q,w)*(x[h,w] +/- x[h,w+128])
        const float* __restrict__ twp = TW2 + s * 512;   // uniform -> s_load
#pragma unroll 2
        for (int wl = 0; wl < 16; wl++) {
            float y0 = smem[tid * 33 + wl];        // x[h, 16s+wl]
            float y1 = smem[tid * 33 + 16 + wl];   // x[h, 16s+wl+128]
            float sp = y0 + y1, sm = y0 - y1;
#pragma unroll
            for (int q = 0; q < 16; q++) {
                float sel = (q & 1) ? sm : sp;     // compile-time select
                float cc = twp[wl * 32 + 2 * q];
                float ss = twp[wl * 32 + 2 * q + 1];
                pr[q] = fmaf(sel,  cc, pr[q]);
                pi[q] = fmaf(sel, -ss, pi[q]);
            }
        }
    }

    // ---- dump P to LDS (padded: row stride 34 floats = 17 complex)
    asm volatile("s_waitcnt lgkmcnt(0)" ::: "memory");
    __builtin_amdgcn_s_barrier();
#pragma unroll
    for (int q = 0; q < 16; q++) {
        smem[tid * 34 + 2 * q]     = pr[q];
        smem[tid * 34 + 2 * q + 1] = pi[q];
    }
    asm volatile("s_waitcnt lgkmcnt(0)" ::: "memory");
    __builtin_amdgcn_s_barrier();

    // ---- fold pass: row h (h<128) := P[h]+P[h+128]; row h+128 := P[h]-P[h+128]
#pragma unroll
    for (int k = 0; k < 8; k++) {
        int idx = k * 256 + tid;
        int h = idx >> 4, q = idx & 15;
        float2 a  = *(const float2*)&smem[h * 34 + 2 * q];
        float2 bb = *(const float2*)&smem[(h + 128) * 34 + 2 * q];
        *(float2*)&smem[h * 34 + 2 * q]         = make_float2(a.x + bb.x, a.y + bb.y);
        *(float2*)&smem[(h + 128) * 34 + 2 * q] = make_float2(a.x - bb.x, a.y - bb.y);
    }
    asm volatile("s_waitcnt lgkmcnt(0)" ::: "memory");
    __builtin_amdgcn_s_barrier();

    // ---- Phase B (radix-2 over h): thread parity picks U (even t) or V (odd t)
    {
        const int q  = tid & 15;
        const int tp = tid >> 4;
        const int t0 = tp;
        const int t1 = 240 + tp;
        const int rbase = (tp & 1) ? (128 * 34) : 0;
        float x0r = 0.f, x0i = 0.f, x1r = 0.f, x1i = 0.f;
        for (int h = 0; h < 128; h++) {
            float2 uv = *(const float2*)&smem[rbase + h * 34 + 2 * q];
            float2 e0 = Ecs[(t0 * h) & 255];
            float2 e1 = Ecs[(t1 * h) & 255];
            x0r = fmaf(uv.x, e0.x, fmaf(uv.y,  e0.y, x0r));
            x0i = fmaf(uv.y, e0.x, fmaf(uv.x, -e0.y, x0i));
            x1r = fmaf(uv.x, e1.x, fmaf(uv.y,  e1.y, x1r));
            x1i = fmaf(uv.y, e1.x, fmaf(uv.x, -e1.y, x1i));
        }
        const float sc = 1.0f / 256.0f;
        const int b = img >> 6, c = img & 63;
        size_t o0 = ((size_t)(tp * 16 + q) * 64 + c) * 16 + b;         // mode tp
        size_t o1 = ((size_t)((16 + tp) * 16 + q) * 64 + c) * 16 + b;  // mode 16+tp
        Xg[2 * o0]     = x0r * sc;
        Xg[2 * o0 + 1] = x0i * sc;
        Xg[2 * o1]     = x1r * sc;
        Xg[2 * o1 + 1] = x1i * sc;
    }
}

// ------------------------------------------------- per-mode channel mix: X -> Y
__global__ __launch_bounds__(256) void k_mix(const float* __restrict__ Xg,
                                             const float* __restrict__ Wt,
                                             float* __restrict__ Yg) {
    __shared__ float Xs[64 * 34];    // [c][b] padded (17 complex stride)
    __shared__ float Ws[64 * 130];   // [d][c] padded (65 complex stride)

    const int tid  = threadIdx.x;
    const int mode = blockIdx.x;

#pragma unroll
    for (int j = 0; j < 4; j++) {    // X: 1024 complex contiguous
        int i = j * 256 + tid;       // c*16+b
        float2 v = ((const float2*)Xg)[(size_t)mode * 1024 + i];
        int c = i >> 4, b = i & 15;
        Xs[c * 34 + 2 * b] = v.x; Xs[c * 34 + 2 * b + 1] = v.y;
    }
#pragma unroll
    for (int j = 0; j < 16; j++) {   // W: 4096 complex contiguous (transposed)
        int i = j * 256 + tid;       // d*64+c
        float2 v = ((const float2*)Wt)[(size_t)mode * 4096 + i];
        int d = i >> 6, c = i & 63;
        Ws[d * 130 + 2 * c] = v.x; Ws[d * 130 + 2 * c + 1] = v.y;
    }
    __syncthreads();

    const int b = tid & 15, dg = tid >> 4;
    float yr[4] = {0, 0, 0, 0}, yi[4] = {0, 0, 0, 0};
    for (int c = 0; c < 64; c++) {
        float xr = Xs[c * 34 + 2 * b];
        float xi = Xs[c * 34 + 2 * b + 1];
#pragma unroll
        for (int j = 0; j < 4; j++) {
            int d = dg + 16 * j;
            float wr = Ws[d * 130 + 2 * c];
            float wi = Ws[d * 130 + 2 * c + 1];
            yr[j] = fmaf(xr, wr, fmaf(xi, -wi, yr[j]));
            yi[j] = fmaf(xr, wi, fmaf(xi,  wr, yi[j]));
        }
    }
#pragma unroll
    for (int j = 0; j < 4; j++) {
        int d = dg + 16 * j;
        size_t o = ((size_t)(b * 64 + d) * 512 + mode);
        Yg[2 * o] = yr[j]; Yg[2 * o + 1] = yi[j];
    }
}

// ------------------------------------------------- inverse: Y -> out
// one block per (b,d) image. Phase E: compute into regs, raw barriers,
// global stores pipeline across slabs (never drained at a barrier).
__global__ __launch_bounds__(256) void k_inv(const float* __restrict__ Yg,
                                             const float* __restrict__ TW2,
                                             float* __restrict__ out) {
    __shared__ float2 Ecs[256];
    __shared__ float  stage[256 * 33];

    const int tid = threadIdx.x;
    const int img = blockIdx.x;      // b*64 + d
    {
        float s, c;
        sincospif((float)tid * (1.0f / 128.0f), &s, &c);
        Ecs[tid] = make_float2(c, s);
    }
    const float* __restrict__ Y = Yg + (size_t)img * 1024;  // 512 complex

    // ---- Phase D: g[h,q] = sum_{t in S} Y[t,q] e^{+2pi i t h/256}, thread h=tid
    float gr[16], gi[16];
#pragma unroll
    for (int q = 0; q < 16; q++) { gr[q] = 0.f; gi[q] = 0.f; }
    __syncthreads();   // Ecs ready
    const int h = tid;
    for (int j = 0; j < 32; j++) {
        int t = (j < 16) ? j : (224 + j);      // 240..255 for bottom block
        float2 e = Ecs[(t * h) & 255];
#pragma unroll
        for (int q = 0; q < 16; q++) {
            float yr = Y[j * 32 + 2 * q];      // uniform -> s_load
            float yv = Y[j * 32 + 2 * q + 1];
            gr[q] = fmaf(yr, e.x, fmaf(yv, -e.y, gr[q]));
            gi[q] = fmaf(yv, e.x, fmaf(yr,  e.y, gi[q]));
        }
    }

    // ---- Phase E (radix-2 over w): out[w]=ae+ao, out[w+128]=ae-ao
    const size_t obase = (size_t)img * (HH * WW);
    const float k2 = 2.0f / 256.0f;
    const int f4   = tid & 7;
    const int hb   = tid >> 3;
    const int colb = ((f4 & 4) << 5) + (f4 & 3) * 4;
    for (int s = 0; s < 8; s++) {
        const float* __restrict__ twp = TW2 + s * 512;   // uniform -> s_load
        float v0[16], v1[16];
#pragma unroll 2
        for (int wl = 0; wl < 16; wl++) {
            float ae = 0.5f * gr[0];
            float ao = 0.f;
#pragma unroll
            for (int q = 1; q < 16; q++) {
                float cc = twp[wl * 32 + 2 * q];
                float ss = twp[wl * 32 + 2 * q + 1];
                if (q & 1) ao = fmaf(gr[q], cc, fmaf(gi[q], -ss, ao));
                else       ae = fmaf(gr[q], cc, fmaf(gi[q], -ss, ae));
            }
            v0[wl] = (ae + ao) * k2;
            v1[wl] = (ae - ao) * k2;
        }
        // previous slab's stage reads retired + barrier, then overwrite stage
        asm volatile("s_waitcnt lgkmcnt(0)" ::: "memory");
        __builtin_amdgcn_s_barrier();
#pragma unroll
        for (int wl = 0; wl < 16; wl++) {
            stage[h * 33 + wl]      = v0[wl];
            stage[h * 33 + 16 + wl] = v1[wl];
        }
        asm volatile("s_waitcnt lgkmcnt(0)" ::: "memory");
        __builtin_amdgcn_s_barrier();
        // coalesced write-out; stores stay in flight across the next barrier
#pragma unroll
        for (int j = 0; j < 8; j++) {
            const float* p = &stage[(j * 32 + hb) * 33 + f4 * 4];
            float4 v; v.x = p[0]; v.y = p[1]; v.z = p[2]; v.w = p[3];
            *(float4*)(out + obase + (size_t)(j * 32 + hb) * WW + 16 * s + colb) = v;
        }
    }
}

extern "C" void kernel_launch(void* const* d_in, const int* in_sizes, int n_in,
                              void* d_out, int out_size, void* d_ws, size_t ws_size,
                              hipStream_t stream) {
    const float* x  = (const float*)d_in[0];
    const float* w1 = (const float*)d_in[1];
    const float* w2 = (const float*)d_in[2];
    float* outp = (float*)d_out;

    float* TW2 = (float*)d_ws;           // 8192 floats
    float* Xg  = TW2 + 8192;             // 1,048,576 floats
    float* Yg  = Xg + 1048576;           // 1,048,576 floats
    float* Wt  = Yg + 1048576;           // 4,194,304 floats

    k_twiddle<<<16,   256, 0, stream>>>(TW2);
    k_wt     <<<2048, 256, 0, stream>>>(w1, w2, Wt);
    k_fwd    <<<BB * CIN, 256, 0, stream>>>(x, TW2, Xg);
    k_mix    <<<512,  256, 0, stream>>>(Xg, Wt, Yg);
    k_inv    <<<BB * CIN, 256, 0, stream>>>(Yg, TW2, outp);
}